// Round 10
// baseline (237.337 us; speedup 1.0000x reference)
//
#include <hip/hip_runtime.h>
#include <stdint.h>
#include <stddef.h>

// DecoderMHA: x[4,2048,1024] fp32 -> out fp32 [4,2048,1024]
// cvt(fused) -> QKV gemm (fine-phase, V transposed epilogue) ->
// flash attn (R7 structure: best measured, 62.0us) -> out proj.
//
// GEMM core: 128x256 tile, BK=32, 8 waves, triple-buffered LDS (72KB).
// Per K-tile: {8 ds_read_b128; 3 global_load_lds; s_barrier; lgkmcnt(0);
// setprio(1); 16 MFMA; setprio(0); vmcnt(3); s_barrier}.
//
// Attn: 256 blocks x 512 thr (8 waves x 32 q-rows = 256-row q-tile), causal
// pairing (t,7-t) -> uniform 36 x 64-key tiles/block; wave-uniform diagonal
// mask branch. Structural-attempt ledger (all reverted): 2-block/CU split
// (R5/R8: no co-residency, serial rounds), ones-MFMA denom + setprio (R6:
// lockstep block = m190 regime), deferred-PV (R9: +32 VGPR, longer lgkm
// chain). R7 plain structure is the measured floor: 62.0us, 96 VGPR.

typedef __bf16 bf16;
typedef __bf16 bf16x8 __attribute__((ext_vector_type(8)));
typedef __bf16 bf16x4 __attribute__((ext_vector_type(4)));
typedef float f32x4 __attribute__((ext_vector_type(4)));

#define DM   1024
#define NH   16
#define DK   64
#define BSZ  4
#define SEQL 2048
#define NTOK 8192   // BSZ*SEQL
#define NEGB -3.0e38f

__device__ __forceinline__ void async16(const bf16* g, void* l) {
  __builtin_amdgcn_global_load_lds(
      (__attribute__((address_space(1))) void*)g,
      (__attribute__((address_space(3))) void*)l, 16, 0, 0);
}

// ---------------- fused converts: x->bf16, W*4->bf16, pad->float bias ----------
__global__ __launch_bounds__(256) void cvt_all(
    const float* __restrict__ x,
    const float* __restrict__ w0, const float* __restrict__ w1,
    const float* __restrict__ w2, const float* __restrict__ w3,
    const int* __restrict__ pad,
    bf16* __restrict__ xd,
    bf16* __restrict__ d0, bf16* __restrict__ d1,
    bf16* __restrict__ d2, bf16* __restrict__ d3,
    float* __restrict__ padf) {
  int blk = blockIdx.x;
  if (blk >= 6144) {  // pad bias: 4 blocks x 2048 entries
    int i = (blk - 6144) * 2048 + threadIdx.x * 8;
    int4 p0 = *(const int4*)(pad + i);
    int4 p1 = *(const int4*)(pad + i + 4);
    float4 o0 = {p0.x ? NEGB : 0.f, p0.y ? NEGB : 0.f, p0.z ? NEGB : 0.f, p0.w ? NEGB : 0.f};
    float4 o1 = {p1.x ? NEGB : 0.f, p1.y ? NEGB : 0.f, p1.z ? NEGB : 0.f, p1.w ? NEGB : 0.f};
    *(float4*)(padf + i) = o0;
    *(float4*)(padf + i + 4) = o1;
    return;
  }
  const float* s; bf16* d; int i;
  if (blk < 4096) { s = x; d = xd; i = blk * 2048 + threadIdx.x * 8; }
  else {
    int m = (blk - 4096) >> 9, bi = (blk - 4096) & 511;
    switch (m) {
      case 0:  s = w0; d = d0; break;
      case 1:  s = w1; d = d1; break;
      case 2:  s = w2; d = d2; break;
      default: s = w3; d = d3; break;
    }
    i = bi * 2048 + threadIdx.x * 8;
  }
  float4 v0 = *(const float4*)(s + i);
  float4 v1 = *(const float4*)(s + i + 4);
  bf16x8 o = {(bf16)v0.x, (bf16)v0.y, (bf16)v0.z, (bf16)v0.w,
              (bf16)v1.x, (bf16)v1.y, (bf16)v1.z, (bf16)v1.w};
  *(bf16x8*)(d + i) = o;
}

// ---------------- fine-phase bf16 GEMM core, 128x256, BK=32, triple-buffer -----
// (unchanged since R4)
template <int OUT_MODE>
__device__ __forceinline__ void gemm_fine(const bf16* __restrict__ A,
                                          const bf16* __restrict__ W,
                                          const float* __restrict__ bias,
                                          void* __restrict__ outp,
                                          int bm, int bn, char* smem) {
  const int tid  = threadIdx.x;
  const int lane = tid & 63;
  const int wv   = tid >> 6;
  const int wr   = wv >> 2;            // M half (64 rows)
  const int wc   = wv & 3;             // N quarter (64 cols)
  const int c    = lane & 15;
  const int quad = lane >> 4;

  char* Ab = smem;                     // 3 x 8192
  char* Bb = smem + 24576;             // 3 x 16384

  const int sr  = tid >> 2;            // 0..127
  const int sjj = ((tid & 3) ^ (sr & 3)) * 8;
  const bf16* gA = A + (size_t)(bm + sr) * DM + sjj;
  const bf16* gB = W + (size_t)(bn + sr) * DM + sjj;

#define STG(KT, U) {                                                     \
    async16(gA + (size_t)(KT) * 32, Ab + (U) * 8192 + tid * 16);         \
    async16(gB + (size_t)(KT) * 32, Bb + (U) * 16384 + tid * 16);        \
    async16(gB + (size_t)(KT) * 32 + (size_t)128 * DM,                   \
            Bb + (U) * 16384 + 8192 + tid * 16); }

  const int sw = (quad ^ (c & 3)) * 16;
  int aoff[4], boff[4];
#pragma unroll
  for (int i = 0; i < 4; ++i) {
    aoff[i] = (wr * 64 + i * 16 + c) * 64 + sw;
    boff[i] = (wc * 64 + i * 16 + c) * 64 + sw;
  }

  f32x4 acc[4][4] = {};

  STG(0, 0) STG(1, 1)
  asm volatile("s_waitcnt vmcnt(3)" ::: "memory");
  __builtin_amdgcn_s_barrier();
  __builtin_amdgcn_sched_barrier(0);

#pragma unroll
  for (int kt = 0; kt < 32; ++kt) {
    const char* Ac = Ab + (kt % 3) * 8192;
    const char* Bc = Bb + (kt % 3) * 16384;
    bf16x8 a[4], b[4];
#pragma unroll
    for (int i = 0; i < 4; ++i) a[i] = *(const bf16x8*)(Ac + aoff[i]);
#pragma unroll
    for (int i = 0; i < 4; ++i) b[i] = *(const bf16x8*)(Bc + boff[i]);
    if (kt + 2 < 32) STG(kt + 2, (kt + 2) % 3)
    __builtin_amdgcn_s_barrier();
    asm volatile("s_waitcnt lgkmcnt(0)" ::: "memory");
    __builtin_amdgcn_sched_barrier(0);
    __builtin_amdgcn_s_setprio(1);
#pragma unroll
    for (int mi = 0; mi < 4; ++mi)
#pragma unroll
      for (int ni = 0; ni < 4; ++ni)
        acc[mi][ni] = __builtin_amdgcn_mfma_f32_16x16x32_bf16(a[mi], b[ni],
                                                              acc[mi][ni], 0, 0, 0);
    __builtin_amdgcn_s_setprio(0);
    if (kt <= 29)      asm volatile("s_waitcnt vmcnt(3)" ::: "memory");
    else if (kt == 30) asm volatile("s_waitcnt vmcnt(0)" ::: "memory");
    if (kt != 31) {
      __builtin_amdgcn_s_barrier();
      __builtin_amdgcn_sched_barrier(0);
    }
  }
#undef STG

  float bias_r[4];
#pragma unroll
  for (int ni = 0; ni < 4; ++ni) bias_r[ni] = bias[bn + wc * 64 + ni * 16 + c];

  if constexpr (OUT_MODE == 2) {
    __syncthreads();
    bf16* vt = (bf16*)smem + wv * 4608;  // 64*72 elements per wave
#pragma unroll
    for (int mi = 0; mi < 4; ++mi)
#pragma unroll
      for (int ni = 0; ni < 4; ++ni) {
        bf16x4 pv = {(bf16)(acc[mi][ni][0] + bias_r[ni]),
                     (bf16)(acc[mi][ni][1] + bias_r[ni]),
                     (bf16)(acc[mi][ni][2] + bias_r[ni]),
                     (bf16)(acc[mi][ni][3] + bias_r[ni])};
        *(bf16x4*)&vt[(ni * 16 + c) * 72 + mi * 16 + quad * 4] = pv;
      }
    const int base = bm + wr * 64;
    const int bb = base >> 11, s0 = base & 2047;
    const int rl = lane >> 3, cl = lane & 7;
#pragma unroll
    for (int it = 0; it < 8; ++it) {
      int d_row = it * 8 + rl;
      bf16x8 v = *(const bf16x8*)&vt[d_row * 72 + cl * 8];
      int n_g = bn + wc * 64 + d_row;
      int hh = n_g >> 6, dd = n_g & 63;
      *(bf16x8*)&((bf16*)outp)[(((size_t)(bb * NH + hh)) * DK + dd) * SEQL + s0 + cl * 8] = v;
    }
    return;
  }

#pragma unroll
  for (int mi = 0; mi < 4; ++mi) {
#pragma unroll
    for (int reg = 0; reg < 4; ++reg) {
      int m_g = bm + wr * 64 + mi * 16 + quad * 4 + reg;
#pragma unroll
      for (int ni = 0; ni < 4; ++ni) {
        int n_g = bn + wc * 64 + ni * 16 + c;
        float v = acc[mi][ni][reg] + bias_r[ni];
        if constexpr (OUT_MODE == 0) {
          int b = m_g >> 11, s = m_g & 2047;
          int h = n_g >> 6, d = n_g & 63;
          ((bf16*)outp)[(((size_t)(b * NH + h) * SEQL + s) << 6) + d] = (bf16)v;
        } else {
          ((float*)outp)[(size_t)m_g * DM + n_g] = v;
        }
      }
    }
  }
}

__global__ __launch_bounds__(512, 4) void qkv_gemm(
    const bf16* __restrict__ X,
    const bf16* __restrict__ Wq, const bf16* __restrict__ Wk, const bf16* __restrict__ Wv,
    const float* __restrict__ bq, const float* __restrict__ bk, const float* __restrict__ bv,
    bf16* __restrict__ Q, bf16* __restrict__ K, bf16* __restrict__ Vt) {
  __shared__ alignas(16) char smem[73728];
  const int f   = blockIdx.x;            // 0..767
  const int xcd = f & 7;
  const int c96 = f >> 3;                // 0..95 within XCD
  const int z   = c96 >> 5;              // 0:Q 1:K 2:V
  const int r   = c96 & 31;
  const int bm  = (xcd * 8 + (r >> 2)) * 128;
  const int bn  = (r & 3) * 256;
  if (z == 0)      gemm_fine<0>(X, Wq, bq, Q,  bm, bn, smem);
  else if (z == 1) gemm_fine<0>(X, Wk, bk, K,  bm, bn, smem);
  else             gemm_fine<2>(X, Wv, bv, Vt, bm, bn, smem);
}

__global__ __launch_bounds__(512, 4) void out_gemm(const bf16* __restrict__ A,
                                                   const bf16* __restrict__ W,
                                                   const float* __restrict__ bias,
                                                   float* __restrict__ out) {
  __shared__ alignas(16) char smem[73728];
  const int f   = blockIdx.x;
  const int c32 = f >> 3;
  const int bm  = ((f & 7) * 8 + (c32 >> 2)) * 128;
  const int bn  = (c32 & 3) * 256;
  gemm_fine<1>(A, W, bias, out, bm, bn, smem);
}

// ---------------- flash attention: 8 waves x 32 q-rows, 256-row q-tile ----------
// 256 blocks (1/CU), causal pairing (t, 7-t): 36 x 64-key tiles per block.
// K LDS [64 key][64 d], V LDS [64 d][64 key]: 128B rows, 3-bit XOR chunk swz;
// P LDS [32 q][64 k] per wave, same swizzle. Diagonal mask in wave-uniform
// dg branch. (Exact R7 structure — best measured: 62.0us.)
__global__ __launch_bounds__(512, 2) void attn_kernel(
    const bf16* __restrict__ Q, const bf16* __restrict__ K,
    const bf16* __restrict__ Vt, const float* __restrict__ padf,
    bf16* __restrict__ O) {
  const int B = blockIdx.x;              // 0..255
  const int bh = (B & 7) + 8 * (B >> 5); // 8 bh per XCD (KV set = 4MB = one L2)
  const int t  = (B >> 3) & 3;           // pair index 0..3
  const int b = bh >> 4, h = bh & 15;
  const int tid  = threadIdx.x;
  const int lane = tid & 63;
  const int wv   = tid >> 6;             // 0..7
  const int c    = lane & 15;
  const int quad = lane >> 4;

  __shared__ bf16 Ks[2][64 * 64];        // [key][d], 128B rows, XOR-3 chunk swz
  __shared__ bf16 Vs[2][64 * 64];        // [d][key], 128B rows, XOR-3 chunk swz
  __shared__ bf16 Pl_all[8][32 * 64];    // per-wave P, 128B rows, XOR-3 chunk swz
  bf16* Pl = &Pl_all[wv][0];

  const bf16* Qh  = Q  + (size_t)bh * SEQL * DK;
  const bf16* Kh  = K  + (size_t)bh * SEQL * DK;
  const bf16* Vth = Vt + (size_t)bh * DK * SEQL;
  const float* pb = padf + b * SEQL;

  const int sr = tid >> 3;                      // 0..63
  const int sj = ((tid & 7) ^ (sr & 7)) * 8;    // swizzled source element offset
  const bf16* gK = Kh  + (size_t)sr * DK   + sj;
  const bf16* gV = Vth + (size_t)sr * SEQL + sj;
  bf16* lK0 = &Ks[0][tid * 8]; bf16* lK1 = &Ks[1][tid * 8];
  bf16* lV0 = &Vs[0][tid * 8]; bf16* lV1 = &Vs[1][tid * 8];

  const float sc = 0.1803368801111204f;  // log2(e) / sqrt(64)

  for (int pass = 0; pass < 2; ++pass) {
    const int qt  = pass ? 7 - t : t;    // 256-row q-tile index
    const int R   = qt * 256 + wv * 32;  // wave's first q row
    const int nkt = (qt + 1) * 4;        // 64-key tiles

    bf16x8 Qf[2][2];
#pragma unroll
    for (int qg = 0; qg < 2; ++qg)
#pragma unroll
      for (int kh = 0; kh < 2; ++kh)
        Qf[qg][kh] = *(const bf16x8*)&Qh[(size_t)(R + qg * 16 + c) * DK + kh * 32 + quad * 8];

    f32x4 Oc[2][4] = {};
    float ls[2] = {0.f, 0.f};

    __syncthreads();
    async16(gK, lK0);
    async16(gV, lV0);

    for (int kt = 0; kt < nkt; ++kt) {
      const int cur = kt & 1;
      const int kb = kt * 64;
      __syncthreads();  // drains asyncs: buf[cur] ready; buf[cur^1] free

      if (kt + 1 < nkt) {
        async16(gK + (size_t)(kt + 1) * 64 * DK, cur ? lK0 : lK1);
        async16(gV + (size_t)(kt + 1) * 64,      cur ? lV0 : lV1);
      }
      if (kb > R + 31) continue;  // fully masked for this wave

      float4 bc[4];
#pragma unroll
      for (int kf = 0; kf < 4; ++kf)
        bc[kf] = *(const float4*)&pb[kb + kf * 16 + quad * 4];

      const bf16* Kc = cur ? Ks[1] : Ks[0];
      const bf16* Vc = cur ? Vs[1] : Vs[0];

      // LDS -> fragments (shared across both query groups)
      bf16x8 Kf[4][2], Vf[4][2];
#pragma unroll
      for (int kf = 0; kf < 4; ++kf)
#pragma unroll
        for (int kh = 0; kh < 2; ++kh)
          Kf[kf][kh] = *(const bf16x8*)&Kc[(kf * 16 + c) * 64 + (((kh * 4 + quad) ^ (c & 7)) * 8)];
#pragma unroll
      for (int df = 0; df < 4; ++df)
#pragma unroll
        for (int kv = 0; kv < 2; ++kv)
          Vf[df][kv] = *(const bf16x8*)&Vc[(df * 16 + c) * 64 + (((kv * 4 + quad) ^ (c & 7)) * 8)];

      // S^T = K.Q^T  (col=query, row=key); st[qg][kf]: key = kf*16 + quad*4 + r
      f32x4 st[2][4] = {};
#pragma unroll
      for (int qg = 0; qg < 2; ++qg)
#pragma unroll
        for (int kh = 0; kh < 2; ++kh)
#pragma unroll
          for (int kf = 0; kf < 4; ++kf)
            st[qg][kf] = __builtin_amdgcn_mfma_f32_16x16x32_bf16(Kf[kf][kh], Qf[qg][kh],
                                                                 st[qg][kf], 0, 0, 0);

      // softmax (no max-subtraction) + P store; masked keys -> exp2(-3e38)=0.
      // dg is WAVE-UNIFORM: only diagonal tiles pay per-element cmp/cndmask.
      if (kb + 63 > R) {
#pragma unroll
        for (int qg = 0; qg < 2; ++qg) {
          const int qrow = R + qg * 16 + c;
#pragma unroll
          for (int kf = 0; kf < 4; ++kf) {
            const float* bv4 = (const float*)&bc[kf];
            float p4[4];
#pragma unroll
            for (int r = 0; r < 4; ++r) {
              float e = __builtin_amdgcn_exp2f(__builtin_fmaf(st[qg][kf][r], sc, bv4[r]));
              if (kb + kf * 16 + quad * 4 + r > qrow) e = 0.f;
              p4[r] = e;
              ls[qg] += e;
            }
            bf16x4 pk = {(bf16)p4[0], (bf16)p4[1], (bf16)p4[2], (bf16)p4[3]};
            *(bf16x4*)&Pl[(qg * 16 + c) * 64 +
                          (((kf * 2 + (quad >> 1)) ^ (c & 7)) * 8) + (quad & 1) * 4] = pk;
          }
        }
      } else {
#pragma unroll
        for (int qg = 0; qg < 2; ++qg) {
#pragma unroll
          for (int kf = 0; kf < 4; ++kf) {
            const float* bv4 = (const float*)&bc[kf];
            float p4[4];
#pragma unroll
            for (int r = 0; r < 4; ++r) {
              float e = __builtin_amdgcn_exp2f(__builtin_fmaf(st[qg][kf][r], sc, bv4[r]));
              p4[r] = e;
              ls[qg] += e;
            }
            bf16x4 pk = {(bf16)p4[0], (bf16)p4[1], (bf16)p4[2], (bf16)p4[3]};
            *(bf16x4*)&Pl[(qg * 16 + c) * 64 +
                          (((kf * 2 + (quad >> 1)) ^ (c & 7)) * 8) + (quad & 1) * 4] = pk;
          }
        }
      }

      // O += P @ V   (af key order == Vf key order)
#pragma unroll
      for (int qg = 0; qg < 2; ++qg)
#pragma unroll
        for (int kv = 0; kv < 2; ++kv) {
          bf16x8 af = *(const bf16x8*)&Pl[(qg * 16 + c) * 64 +
                                          (((kv * 4 + quad) ^ (c & 7)) * 8)];
#pragma unroll
          for (int df = 0; df < 4; ++df)
            Oc[qg][df] = __builtin_amdgcn_mfma_f32_16x16x32_bf16(af, Vf[df][kv],
                                                                 Oc[qg][df], 0, 0, 0);
        }
    }

    // epilogue: reduce l across quads, divide, store
#pragma unroll
    for (int qg = 0; qg < 2; ++qg) {
      float l = ls[qg];
      l += __shfl_xor(l, 16);
      l += __shfl_xor(l, 32);
      float linv = (l > 0.f) ? 1.f / l : 0.f;
      float lr[4];
#pragma unroll
      for (int r = 0; r < 4; ++r) lr[r] = __shfl(linv, quad * 4 + r);
#pragma unroll
      for (int r = 0; r < 4; ++r) {
        size_t row = (size_t)(b * SEQL + R + qg * 16 + quad * 4 + r) * DM + h * DK;
#pragma unroll
        for (int df = 0; df < 4; ++df)
          O[row + df * 16 + c] = (bf16)(Oc[qg][df][r] * lr[r]);
      }
    }
  }
}

// ---------------- launch ----------------
extern "C" void kernel_launch(void* const* d_in, const int* in_sizes, int n_in,
                              void* d_out, int out_size, void* d_ws, size_t ws_size,
                              hipStream_t stream) {
  const float* x   = (const float*)d_in[0];
  const int*   pad = (const int*)d_in[1];
  const float* Wq  = (const float*)d_in[2];
  const float* bq  = (const float*)d_in[3];
  const float* Wk  = (const float*)d_in[4];
  const float* bk  = (const float*)d_in[5];
  const float* Wv  = (const float*)d_in[6];
  const float* bv  = (const float*)d_in[7];
  const float* Wo  = (const float*)d_in[8];
  const float* bo  = (const float*)d_in[9];
  float* out = (float*)d_out;

  const size_t SZ_X = (size_t)NTOK * DM * 2;  // 16 MB
  const size_t SZ_W = (size_t)DM * DM * 2;    // 2 MB
  char* ws = (char*)d_ws;
  bf16* Xb  = (bf16*)ws;  ws += SZ_X;
  bf16* Wqb = (bf16*)ws;  ws += SZ_W;
  bf16* Wkb = (bf16*)ws;  ws += SZ_W;
  bf16* Wvb = (bf16*)ws;  ws += SZ_W;
  bf16* Wob = (bf16*)ws;  ws += SZ_W;
  bf16* Qb  = (bf16*)ws;  ws += SZ_X;
  bf16* Kb  = (bf16*)ws;  ws += SZ_X;
  bf16* Vtb = (bf16*)ws;  ws += SZ_X;   // [B,H,dk,S]
  bf16* Ob  = (bf16*)ws;  ws += SZ_X;
  float* padfb = (float*)ws; ws += (size_t)NTOK * 4;

  cvt_all<<<6148, 256, 0, stream>>>(x, Wq, Wk, Wv, Wo, pad,
                                    Xb, Wqb, Wkb, Wvb, Wob, padfb);
  qkv_gemm<<<768, 512, 0, stream>>>(Xb, Wqb, Wkb, Wvb, bq, bk, bv, Qb, Kb, Vtb);
  attn_kernel<<<256, 512, 0, stream>>>(Qb, Kb, Vtb, padfb, Ob);
  out_gemm<<<256, 512, 0, stream>>>(Ob, Wob, bo, out);
}

// Round 11
// 233.067 us; speedup vs baseline: 1.0183x; 1.0183x over previous
//
#include <hip/hip_runtime.h>
#include <stdint.h>
#include <stddef.h>

// DecoderMHA: x[4,2048,1024] fp32 -> out fp32 [4,2048,1024]
// cvt(fused) -> QKV gemm (fine-phase, paired-row LDS, V transposed epilogue) ->
// flash attn (R7 structure) -> out proj.
//
// GEMM core: 128x256 tile, BK=32, 8 waves, triple-buffered LDS (72KB ->
// 2 blocks/CU). R11 change: PAIRED-ROW LDS layout — matrix rows 2a,2a+1 share
// one 128B LDS row with 8 slots, logical chunk J=(m&1)*4+j at slot J^(a&7).
// Quarter-wave b128 reads hit each slot exactly 2x = the floor -> removes the
// 4-way conflict of the old 64B-row layout (R10: 6.49M conflict cycles).
// global_load_lds dest stays linear; permutation folded into source address.
//
// Attn: 256 blocks x 512 thr (8 waves x 32 q-rows = 256-row q-tile), causal
// pairing (t,7-t) -> uniform 36 x 64-key tiles/block; wave-uniform diagonal
// mask branch. (R7 structure — best measured 62.0us. Ledger of reverted
// attempts: 2-block split R5/R8, ones-MFMA+setprio R6, deferred-PV R9.)

typedef __bf16 bf16;
typedef __bf16 bf16x8 __attribute__((ext_vector_type(8)));
typedef __bf16 bf16x4 __attribute__((ext_vector_type(4)));
typedef float f32x4 __attribute__((ext_vector_type(4)));

#define DM   1024
#define NH   16
#define DK   64
#define BSZ  4
#define SEQL 2048
#define NTOK 8192   // BSZ*SEQL
#define NEGB -3.0e38f

__device__ __forceinline__ void async16(const bf16* g, void* l) {
  __builtin_amdgcn_global_load_lds(
      (__attribute__((address_space(1))) void*)g,
      (__attribute__((address_space(3))) void*)l, 16, 0, 0);
}

// ---------------- fused converts: x->bf16, W*4->bf16, pad->float bias ----------
__global__ __launch_bounds__(256) void cvt_all(
    const float* __restrict__ x,
    const float* __restrict__ w0, const float* __restrict__ w1,
    const float* __restrict__ w2, const float* __restrict__ w3,
    const int* __restrict__ pad,
    bf16* __restrict__ xd,
    bf16* __restrict__ d0, bf16* __restrict__ d1,
    bf16* __restrict__ d2, bf16* __restrict__ d3,
    float* __restrict__ padf) {
  int blk = blockIdx.x;
  if (blk >= 6144) {  // pad bias: 4 blocks x 2048 entries
    int i = (blk - 6144) * 2048 + threadIdx.x * 8;
    int4 p0 = *(const int4*)(pad + i);
    int4 p1 = *(const int4*)(pad + i + 4);
    float4 o0 = {p0.x ? NEGB : 0.f, p0.y ? NEGB : 0.f, p0.z ? NEGB : 0.f, p0.w ? NEGB : 0.f};
    float4 o1 = {p1.x ? NEGB : 0.f, p1.y ? NEGB : 0.f, p1.z ? NEGB : 0.f, p1.w ? NEGB : 0.f};
    *(float4*)(padf + i) = o0;
    *(float4*)(padf + i + 4) = o1;
    return;
  }
  const float* s; bf16* d; int i;
  if (blk < 4096) { s = x; d = xd; i = blk * 2048 + threadIdx.x * 8; }
  else {
    int m = (blk - 4096) >> 9, bi = (blk - 4096) & 511;
    switch (m) {
      case 0:  s = w0; d = d0; break;
      case 1:  s = w1; d = d1; break;
      case 2:  s = w2; d = d2; break;
      default: s = w3; d = d3; break;
    }
    i = bi * 2048 + threadIdx.x * 8;
  }
  float4 v0 = *(const float4*)(s + i);
  float4 v1 = *(const float4*)(s + i + 4);
  bf16x8 o = {(bf16)v0.x, (bf16)v0.y, (bf16)v0.z, (bf16)v0.w,
              (bf16)v1.x, (bf16)v1.y, (bf16)v1.z, (bf16)v1.w};
  *(bf16x8*)(d + i) = o;
}

// ---------------- fine-phase bf16 GEMM core, 128x256, BK=32, triple-buffer -----
// Paired-row LDS layout (R11): LDS row a (128B, 8 slots) holds matrix rows
// 2a,2a+1; logical chunk J = (m&1)*4 + j stored at slot J ^ (a&7).
// Staging: thread t writes dest t*16 (LDS row t>>3, slot t&7) -> source is
// matrix row 2*(t>>3) + (Jt>>2), k-chunk Jt&3 with Jt = (t&7)^((t>>3)&7).
// Read (row m, k-chunk quad): byte = (m>>1)*128 + (((m&1)*4+quad)^((m>>1)&7))*16.
// OUT_MODE 0: bf16 head-split [B,H,S,dk]; 1: fp32 flat; 2: bf16 transposed
// [B,H,dk,S] via per-wave LDS transpose.
template <int OUT_MODE>
__device__ __forceinline__ void gemm_fine(const bf16* __restrict__ A,
                                          const bf16* __restrict__ W,
                                          const float* __restrict__ bias,
                                          void* __restrict__ outp,
                                          int bm, int bn, char* smem) {
  const int tid  = threadIdx.x;
  const int lane = tid & 63;
  const int wv   = tid >> 6;
  const int wr   = wv >> 2;            // M half (64 rows)
  const int wc   = wv & 3;             // N quarter (64 cols)
  const int c    = lane & 15;
  const int quad = lane >> 4;

  char* Ab = smem;                     // 3 x 8192
  char* Bb = smem + 24576;             // 3 x 16384

  // staging constants (paired-row source remap)
  const int sa  = tid >> 3;                    // LDS row 0..63
  const int sJ  = (tid & 7) ^ (sa & 7);        // logical chunk at this slot
  const int sm  = 2 * sa + (sJ >> 2);          // matrix row 0..127
  const int sjj = (sJ & 3) * 8;                // element offset in 32-k row
  const bf16* gA = A + (size_t)(bm + sm) * DM + sjj;
  const bf16* gB = W + (size_t)(bn + sm) * DM + sjj;

#define STG(KT, U) {                                                     \
    async16(gA + (size_t)(KT) * 32, Ab + (U) * 8192 + tid * 16);         \
    async16(gB + (size_t)(KT) * 32, Bb + (U) * 16384 + tid * 16);        \
    async16(gB + (size_t)(KT) * 32 + (size_t)128 * DM,                   \
            Bb + (U) * 16384 + 8192 + tid * 16); }

  int aoff[4], boff[4];
#pragma unroll
  for (int i = 0; i < 4; ++i) {
    const int ma = wr * 64 + i * 16 + c;
    const int aa = ma >> 1;
    aoff[i] = aa * 128 + (((((ma & 1) << 2) | quad) ^ (aa & 7)) << 4);
    const int mb = wc * 64 + i * 16 + c;
    const int ab = mb >> 1;
    boff[i] = ab * 128 + (((((mb & 1) << 2) | quad) ^ (ab & 7)) << 4);
  }

  f32x4 acc[4][4] = {};

  STG(0, 0) STG(1, 1)
  asm volatile("s_waitcnt vmcnt(3)" ::: "memory");
  __builtin_amdgcn_s_barrier();
  __builtin_amdgcn_sched_barrier(0);

#pragma unroll
  for (int kt = 0; kt < 32; ++kt) {
    const char* Ac = Ab + (kt % 3) * 8192;
    const char* Bc = Bb + (kt % 3) * 16384;
    bf16x8 a[4], b[4];
#pragma unroll
    for (int i = 0; i < 4; ++i) a[i] = *(const bf16x8*)(Ac + aoff[i]);
#pragma unroll
    for (int i = 0; i < 4; ++i) b[i] = *(const bf16x8*)(Bc + boff[i]);
    if (kt + 2 < 32) STG(kt + 2, (kt + 2) % 3)
    __builtin_amdgcn_s_barrier();
    asm volatile("s_waitcnt lgkmcnt(0)" ::: "memory");
    __builtin_amdgcn_sched_barrier(0);
    __builtin_amdgcn_s_setprio(1);
#pragma unroll
    for (int mi = 0; mi < 4; ++mi)
#pragma unroll
      for (int ni = 0; ni < 4; ++ni)
        acc[mi][ni] = __builtin_amdgcn_mfma_f32_16x16x32_bf16(a[mi], b[ni],
                                                              acc[mi][ni], 0, 0, 0);
    __builtin_amdgcn_s_setprio(0);
    if (kt <= 29)      asm volatile("s_waitcnt vmcnt(3)" ::: "memory");
    else if (kt == 30) asm volatile("s_waitcnt vmcnt(0)" ::: "memory");
    if (kt != 31) {
      __builtin_amdgcn_s_barrier();
      __builtin_amdgcn_sched_barrier(0);
    }
  }
#undef STG

  float bias_r[4];
#pragma unroll
  for (int ni = 0; ni < 4; ++ni) bias_r[ni] = bias[bn + wc * 64 + ni * 16 + c];

  if constexpr (OUT_MODE == 2) {
    __syncthreads();
    bf16* vt = (bf16*)smem + wv * 4608;  // 64*72 elements per wave
#pragma unroll
    for (int mi = 0; mi < 4; ++mi)
#pragma unroll
      for (int ni = 0; ni < 4; ++ni) {
        bf16x4 pv = {(bf16)(acc[mi][ni][0] + bias_r[ni]),
                     (bf16)(acc[mi][ni][1] + bias_r[ni]),
                     (bf16)(acc[mi][ni][2] + bias_r[ni]),
                     (bf16)(acc[mi][ni][3] + bias_r[ni])};
        *(bf16x4*)&vt[(ni * 16 + c) * 72 + mi * 16 + quad * 4] = pv;
      }
    const int base = bm + wr * 64;
    const int bb = base >> 11, s0 = base & 2047;
    const int rl = lane >> 3, cl = lane & 7;
#pragma unroll
    for (int it = 0; it < 8; ++it) {
      int d_row = it * 8 + rl;
      bf16x8 v = *(const bf16x8*)&vt[d_row * 72 + cl * 8];
      int n_g = bn + wc * 64 + d_row;
      int hh = n_g >> 6, dd = n_g & 63;
      *(bf16x8*)&((bf16*)outp)[(((size_t)(bb * NH + hh)) * DK + dd) * SEQL + s0 + cl * 8] = v;
    }
    return;
  }

#pragma unroll
  for (int mi = 0; mi < 4; ++mi) {
#pragma unroll
    for (int reg = 0; reg < 4; ++reg) {
      int m_g = bm + wr * 64 + mi * 16 + quad * 4 + reg;
#pragma unroll
      for (int ni = 0; ni < 4; ++ni) {
        int n_g = bn + wc * 64 + ni * 16 + c;
        float v = acc[mi][ni][reg] + bias_r[ni];
        if constexpr (OUT_MODE == 0) {
          int b = m_g >> 11, s = m_g & 2047;
          int h = n_g >> 6, d = n_g & 63;
          ((bf16*)outp)[(((size_t)(b * NH + h) * SEQL + s) << 6) + d] = (bf16)v;
        } else {
          ((float*)outp)[(size_t)m_g * DM + n_g] = v;
        }
      }
    }
  }
}

__global__ __launch_bounds__(512, 4) void qkv_gemm(
    const bf16* __restrict__ X,
    const bf16* __restrict__ Wq, const bf16* __restrict__ Wk, const bf16* __restrict__ Wv,
    const float* __restrict__ bq, const float* __restrict__ bk, const float* __restrict__ bv,
    bf16* __restrict__ Q, bf16* __restrict__ K, bf16* __restrict__ Vt) {
  __shared__ alignas(16) char smem[73728];
  const int f   = blockIdx.x;            // 0..767
  const int xcd = f & 7;
  const int c96 = f >> 3;                // 0..95 within XCD
  const int z   = c96 >> 5;              // 0:Q 1:K 2:V
  const int r   = c96 & 31;
  const int bm  = (xcd * 8 + (r >> 2)) * 128;
  const int bn  = (r & 3) * 256;
  if (z == 0)      gemm_fine<0>(X, Wq, bq, Q,  bm, bn, smem);
  else if (z == 1) gemm_fine<0>(X, Wk, bk, K,  bm, bn, smem);
  else             gemm_fine<2>(X, Wv, bv, Vt, bm, bn, smem);
}

__global__ __launch_bounds__(512, 4) void out_gemm(const bf16* __restrict__ A,
                                                   const bf16* __restrict__ W,
                                                   const float* __restrict__ bias,
                                                   float* __restrict__ out) {
  __shared__ alignas(16) char smem[73728];
  const int f   = blockIdx.x;
  const int c32 = f >> 3;
  const int bm  = ((f & 7) * 8 + (c32 >> 2)) * 128;
  const int bn  = (c32 & 3) * 256;
  gemm_fine<1>(A, W, bias, out, bm, bn, smem);
}

// ---------------- flash attention: 8 waves x 32 q-rows, 256-row q-tile ----------
// (exact R7 structure — best measured: 62.0us)
__global__ __launch_bounds__(512, 2) void attn_kernel(
    const bf16* __restrict__ Q, const bf16* __restrict__ K,
    const bf16* __restrict__ Vt, const float* __restrict__ padf,
    bf16* __restrict__ O) {
  const int B = blockIdx.x;              // 0..255
  const int bh = (B & 7) + 8 * (B >> 5); // 8 bh per XCD (KV set = 4MB = one L2)
  const int t  = (B >> 3) & 3;           // pair index 0..3
  const int b = bh >> 4, h = bh & 15;
  const int tid  = threadIdx.x;
  const int lane = tid & 63;
  const int wv   = tid >> 6;             // 0..7
  const int c    = lane & 15;
  const int quad = lane >> 4;

  __shared__ bf16 Ks[2][64 * 64];        // [key][d], 128B rows, XOR-3 chunk swz
  __shared__ bf16 Vs[2][64 * 64];        // [d][key], 128B rows, XOR-3 chunk swz
  __shared__ bf16 Pl_all[8][32 * 64];    // per-wave P, 128B rows, XOR-3 chunk swz
  bf16* Pl = &Pl_all[wv][0];

  const bf16* Qh  = Q  + (size_t)bh * SEQL * DK;
  const bf16* Kh  = K  + (size_t)bh * SEQL * DK;
  const bf16* Vth = Vt + (size_t)bh * DK * SEQL;
  const float* pb = padf + b * SEQL;

  const int sr = tid >> 3;                      // 0..63
  const int sj = ((tid & 7) ^ (sr & 7)) * 8;    // swizzled source element offset
  const bf16* gK = Kh  + (size_t)sr * DK   + sj;
  const bf16* gV = Vth + (size_t)sr * SEQL + sj;
  bf16* lK0 = &Ks[0][tid * 8]; bf16* lK1 = &Ks[1][tid * 8];
  bf16* lV0 = &Vs[0][tid * 8]; bf16* lV1 = &Vs[1][tid * 8];

  const float sc = 0.1803368801111204f;  // log2(e) / sqrt(64)

  for (int pass = 0; pass < 2; ++pass) {
    const int qt  = pass ? 7 - t : t;    // 256-row q-tile index
    const int R   = qt * 256 + wv * 32;  // wave's first q row
    const int nkt = (qt + 1) * 4;        // 64-key tiles

    bf16x8 Qf[2][2];
#pragma unroll
    for (int qg = 0; qg < 2; ++qg)
#pragma unroll
      for (int kh = 0; kh < 2; ++kh)
        Qf[qg][kh] = *(const bf16x8*)&Qh[(size_t)(R + qg * 16 + c) * DK + kh * 32 + quad * 8];

    f32x4 Oc[2][4] = {};
    float ls[2] = {0.f, 0.f};

    __syncthreads();
    async16(gK, lK0);
    async16(gV, lV0);

    for (int kt = 0; kt < nkt; ++kt) {
      const int cur = kt & 1;
      const int kb = kt * 64;
      __syncthreads();  // drains asyncs: buf[cur] ready; buf[cur^1] free

      if (kt + 1 < nkt) {
        async16(gK + (size_t)(kt + 1) * 64 * DK, cur ? lK0 : lK1);
        async16(gV + (size_t)(kt + 1) * 64,      cur ? lV0 : lV1);
      }
      if (kb > R + 31) continue;  // fully masked for this wave

      float4 bc[4];
#pragma unroll
      for (int kf = 0; kf < 4; ++kf)
        bc[kf] = *(const float4*)&pb[kb + kf * 16 + quad * 4];

      const bf16* Kc = cur ? Ks[1] : Ks[0];
      const bf16* Vc = cur ? Vs[1] : Vs[0];

      // LDS -> fragments (shared across both query groups)
      bf16x8 Kf[4][2], Vf[4][2];
#pragma unroll
      for (int kf = 0; kf < 4; ++kf)
#pragma unroll
        for (int kh = 0; kh < 2; ++kh)
          Kf[kf][kh] = *(const bf16x8*)&Kc[(kf * 16 + c) * 64 + (((kh * 4 + quad) ^ (c & 7)) * 8)];
#pragma unroll
      for (int df = 0; df < 4; ++df)
#pragma unroll
        for (int kv = 0; kv < 2; ++kv)
          Vf[df][kv] = *(const bf16x8*)&Vc[(df * 16 + c) * 64 + (((kv * 4 + quad) ^ (c & 7)) * 8)];

      // S^T = K.Q^T  (col=query, row=key); st[qg][kf]: key = kf*16 + quad*4 + r
      f32x4 st[2][4] = {};
#pragma unroll
      for (int qg = 0; qg < 2; ++qg)
#pragma unroll
        for (int kh = 0; kh < 2; ++kh)
#pragma unroll
          for (int kf = 0; kf < 4; ++kf)
            st[qg][kf] = __builtin_amdgcn_mfma_f32_16x16x32_bf16(Kf[kf][kh], Qf[qg][kh],
                                                                 st[qg][kf], 0, 0, 0);

      // softmax (no max-subtraction) + P store; masked keys -> exp2(-3e38)=0.
      // dg is WAVE-UNIFORM: only diagonal tiles pay per-element cmp/cndmask.
      if (kb + 63 > R) {
#pragma unroll
        for (int qg = 0; qg < 2; ++qg) {
          const int qrow = R + qg * 16 + c;
#pragma unroll
          for (int kf = 0; kf < 4; ++kf) {
            const float* bv4 = (const float*)&bc[kf];
            float p4[4];
#pragma unroll
            for (int r = 0; r < 4; ++r) {
              float e = __builtin_amdgcn_exp2f(__builtin_fmaf(st[qg][kf][r], sc, bv4[r]));
              if (kb + kf * 16 + quad * 4 + r > qrow) e = 0.f;
              p4[r] = e;
              ls[qg] += e;
            }
            bf16x4 pk = {(bf16)p4[0], (bf16)p4[1], (bf16)p4[2], (bf16)p4[3]};
            *(bf16x4*)&Pl[(qg * 16 + c) * 64 +
                          (((kf * 2 + (quad >> 1)) ^ (c & 7)) * 8) + (quad & 1) * 4] = pk;
          }
        }
      } else {
#pragma unroll
        for (int qg = 0; qg < 2; ++qg) {
#pragma unroll
          for (int kf = 0; kf < 4; ++kf) {
            const float* bv4 = (const float*)&bc[kf];
            float p4[4];
#pragma unroll
            for (int r = 0; r < 4; ++r) {
              float e = __builtin_amdgcn_exp2f(__builtin_fmaf(st[qg][kf][r], sc, bv4[r]));
              p4[r] = e;
              ls[qg] += e;
            }
            bf16x4 pk = {(bf16)p4[0], (bf16)p4[1], (bf16)p4[2], (bf16)p4[3]};
            *(bf16x4*)&Pl[(qg * 16 + c) * 64 +
                          (((kf * 2 + (quad >> 1)) ^ (c & 7)) * 8) + (quad & 1) * 4] = pk;
          }
        }
      }

      // O += P @ V   (af key order == Vf key order)
#pragma unroll
      for (int qg = 0; qg < 2; ++qg)
#pragma unroll
        for (int kv = 0; kv < 2; ++kv) {
          bf16x8 af = *(const bf16x8*)&Pl[(qg * 16 + c) * 64 +
                                          (((kv * 4 + quad) ^ (c & 7)) * 8)];
#pragma unroll
          for (int df = 0; df < 4; ++df)
            Oc[qg][df] = __builtin_amdgcn_mfma_f32_16x16x32_bf16(af, Vf[df][kv],
                                                                 Oc[qg][df], 0, 0, 0);
        }
    }

    // epilogue: reduce l across quads, divide, store
#pragma unroll
    for (int qg = 0; qg < 2; ++qg) {
      float l = ls[qg];
      l += __shfl_xor(l, 16);
      l += __shfl_xor(l, 32);
      float linv = (l > 0.f) ? 1.f / l : 0.f;
      float lr[4];
#pragma unroll
      for (int r = 0; r < 4; ++r) lr[r] = __shfl(linv, quad * 4 + r);
#pragma unroll
      for (int r = 0; r < 4; ++r) {
        size_t row = (size_t)(b * SEQL + R + qg * 16 + quad * 4 + r) * DM + h * DK;
#pragma unroll
        for (int df = 0; df < 4; ++df)
          O[row + df * 16 + c] = (bf16)(Oc[qg][df][r] * lr[r]);
      }
    }
  }
}

// ---------------- launch ----------------
extern "C" void kernel_launch(void* const* d_in, const int* in_sizes, int n_in,
                              void* d_out, int out_size, void* d_ws, size_t ws_size,
                              hipStream_t stream) {
  const float* x   = (const float*)d_in[0];
  const int*   pad = (const int*)d_in[1];
  const float* Wq  = (const float*)d_in[2];
  const float* bq  = (const float*)d_in[3];
  const float* Wk  = (const float*)d_in[4];
  const float* bk  = (const float*)d_in[5];
  const float* Wv  = (const float*)d_in[6];
  const float* bv  = (const float*)d_in[7];
  const float* Wo  = (const float*)d_in[8];
  const float* bo  = (const float*)d_in[9];
  float* out = (float*)d_out;

  const size_t SZ_X = (size_t)NTOK * DM * 2;  // 16 MB
  const size_t SZ_W = (size_t)DM * DM * 2;    // 2 MB
  char* ws = (char*)d_ws;
  bf16* Xb  = (bf16*)ws;  ws += SZ_X;
  bf16* Wqb = (bf16*)ws;  ws += SZ_W;
  bf16* Wkb = (bf16*)ws;  ws += SZ_W;
  bf16* Wvb = (bf16*)ws;  ws += SZ_W;
  bf16* Wob = (bf16*)ws;  ws += SZ_W;
  bf16* Qb  = (bf16*)ws;  ws += SZ_X;
  bf16* Kb  = (bf16*)ws;  ws += SZ_X;
  bf16* Vtb = (bf16*)ws;  ws += SZ_X;   // [B,H,dk,S]
  bf16* Ob  = (bf16*)ws;  ws += SZ_X;
  float* padfb = (float*)ws; ws += (size_t)NTOK * 4;

  cvt_all<<<6148, 256, 0, stream>>>(x, Wq, Wk, Wv, Wo, pad,
                                    Xb, Wqb, Wkb, Wvb, Wob, padfb);
  qkv_gemm<<<768, 512, 0, stream>>>(Xb, Wqb, Wkb, Wvb, bq, bk, bv, Qb, Kb, Vtb);
  attn_kernel<<<256, 512, 0, stream>>>(Qb, Kb, Vtb, padfb, Ob);
  out_gemm<<<256, 512, 0, stream>>>(Ob, Wob, bo, out);
}